// Round 3
// baseline (8260.607 us; speedup 1.0000x reference)
//
#include <hip/hip_runtime.h>
#include <hip/hip_bf16.h>
#include <math.h>

// Problem constants
#define NTOT 4096      // B*N nodes
#define NEDGE 65536    // E edges
#define BSZ 64         // batch
#define NN 64          // nodes per trajectory
#define HDIM 1024      // LSTM hidden
#define TIN 10
#define TOUT 6
#define FRAME_ELEMS (NTOT * 2)   // 8192 floats per frame

// ==================== weight transpose: W (NO,K) -> WT (K,NO) ====================
__global__ __launch_bounds__(256) void transpose_kernel(const float* __restrict__ W,
                                                        float* __restrict__ WT,
                                                        int NO, int K) {
    __shared__ float t[32][33];
    int k0 = blockIdx.x * 32;
    int n0 = blockIdx.y * 32;
    int tx = threadIdx.x & 31, ty = threadIdx.x >> 5;  // 32 x 8
    #pragma unroll
    for (int i = 0; i < 4; ++i)
        t[ty + i * 8][tx] = W[(size_t)(n0 + ty + i * 8) * K + k0 + tx];
    __syncthreads();
    #pragma unroll
    for (int i = 0; i < 4; ++i)
        WT[(size_t)(k0 + ty + i * 8) * NO + n0 + tx] = t[tx][ty + i * 8];
}

// ==================== batched GCN over 10 input frames ====================

__global__ void bgcn_init_xw(const float* __restrict__ feat, const float* __restrict__ wg,
                             float* __restrict__ deg, float* __restrict__ xw) {
    int i = blockIdx.x * blockDim.x + threadIdx.x;   // 0..10*4096-1
    if (i >= 10 * NTOT) return;
    deg[i] = 1.0f;   // self loop
    float x0 = feat[i * 2], x1 = feat[i * 2 + 1];
    xw[i * 2]     = x0 * wg[0] + x1 * wg[1];
    xw[i * 2 + 1] = x0 * wg[2] + x1 * wg[3];
}

__global__ void bgcn_count(const int* __restrict__ ei, float* __restrict__ deg) {
    int e = blockIdx.x * blockDim.x + threadIdx.x;   // 0..10*65536-1
    if (e >= 10 * NEDGE) return;
    int t = e >> 16, el = e & 65535;
    int dst = ei[t * 2 * NEDGE + NEDGE + el];
    atomicAdd(&deg[t * NTOT + dst], 1.0f);
}

__global__ void bgcn_node(const float* __restrict__ bg, float* __restrict__ deg,
                          const float* __restrict__ xw, float* __restrict__ gT_all) {
    int i = blockIdx.x * blockDim.x + threadIdx.x;
    if (i >= 10 * NTOT) return;
    float dinv = rsqrtf(deg[i]);
    deg[i] = dinv;
    int t = i >> 12, node = i & 4095;
    int b = node >> 6, nn = node & 63;
    float w2 = dinv * dinv;
    gT_all[t * 8192 + (nn * 2 + 0) * 64 + b] = xw[i * 2]     * w2 + bg[0];
    gT_all[t * 8192 + (nn * 2 + 1) * 64 + b] = xw[i * 2 + 1] * w2 + bg[1];
}

__global__ void bgcn_scatter(const int* __restrict__ ei, const float* __restrict__ dinv,
                             const float* __restrict__ xw, float* __restrict__ gT_all) {
    int e = blockIdx.x * blockDim.x + threadIdx.x;
    if (e >= 10 * NEDGE) return;
    int t = e >> 16, el = e & 65535;
    int s = ei[t * 2 * NEDGE + el];
    int d = ei[t * 2 * NEDGE + NEDGE + el];
    float w = dinv[t * NTOT + s] * dinv[t * NTOT + d];
    int b = d >> 6, nn = d & 63;
    atomicAdd(&gT_all[t * 8192 + (nn * 2 + 0) * 64 + b], xw[(t * NTOT + s) * 2]     * w);
    atomicAdd(&gT_all[t * 8192 + (nn * 2 + 1) * 64 + b], xw[(t * NTOT + s) * 2 + 1] * w);
}

// ==================== fused adjacency + dense GCN (decoder) ====================
// pred: std layout (4096,2) from out frame; gT: (128,64)
__global__ void adj_gcn_kernel(const float* __restrict__ pred,
                               const float* __restrict__ stats,
                               const float* __restrict__ wg,
                               const float* __restrict__ bg,
                               float* __restrict__ gT) {
    int b = blockIdx.x;
    int i = threadIdx.x;   // 64
    __shared__ float f0[NN], f1[NN], sxw0[NN], sxw1[NN], sdinv[NN];
    __shared__ int ex[NN];
    float p0 = pred[(b * NN + i) * 2], p1 = pred[(b * NN + i) * 2 + 1];
    float d0 = p0 * stats[0] + stats[2];
    float d1 = p1 * stats[1] + stats[3];
    f0[i] = d0; f1[i] = d1;
    ex[i] = (d0 > 0.04f) && (d1 > 0.04f);
    sxw0[i] = p0 * wg[0] + p1 * wg[1];
    sxw1[i] = p0 * wg[2] + p1 * wg[3];
    __syncthreads();
    float fi0 = f0[i], fi1 = f1[i];
    int exi = ex[i];
    float deg = 0.f;
    for (int j = 0; j < NN; ++j) {
        float dx = fi0 - f0[j], dy = fi1 - f1[j];
        float a = (i == j) ? 1.0f :
                  ((dx * dx + dy * dy <= 100.0f && exi && ex[j]) ? 1.0f : 0.0f);
        deg += a;
    }
    sdinv[i] = rsqrtf(deg);   // deg >= 1 (self loop)
    __syncthreads();
    float a0 = 0.f, a1 = 0.f;
    for (int j = 0; j < NN; ++j) {
        float dx = fi0 - f0[j], dy = fi1 - f1[j];
        float a = (i == j) ? 1.0f :
                  ((dx * dx + dy * dy <= 100.0f && exi && ex[j]) ? 1.0f : 0.0f);
        float an = a * sdinv[j];
        a0 += an * sxw0[j];
        a1 += an * sxw1[j];
    }
    float di = sdinv[i];
    gT[(i * 2 + 0) * 64 + b] = a0 * di + bg[0];
    gT[(i * 2 + 1) * 64 + b] = a1 * di + bg[1];
}

// ==================== colwave GEMM with fused last-block reduce ====================
// out(64,NO) = act(in(64,K) @ W^T + bias); activations transposed (K,64).
// Split-K: blockIdx.y = ks; ks < SK1 reads inT/WT, else inT2/WT2 (chunk ks-SK1).
// Partials -> P (gridDim.y, NO, 64). If aT != null: last-arriving block per
// n-tile reduces SK partials + bias (+relu), writes aT (NO,64) and optional
// a_std (64,NO).
template<int KC>
__global__ __launch_bounds__(256) void gemm_cw3(
    const float* __restrict__ inT, const float* __restrict__ inT2,
    const float* __restrict__ WT,  const float* __restrict__ WT2,
    float* __restrict__ P, const float* __restrict__ bias,
    float* __restrict__ aT, float* __restrict__ a_std,
    unsigned int* __restrict__ counters,
    int NO, int SK1, int relu)
{
    __shared__ unsigned int last;
    int lane = threadIdx.x & 63;
    int wid = __builtin_amdgcn_readfirstlane(threadIdx.x >> 6);
    int nb = blockIdx.x * 128 + wid * 32;
    int ks = blockIdx.y;
    const float* xs;
    const float* wb;
    if (ks < SK1) { xs = inT  + (size_t)ks * KC * 64;        wb = WT  + (size_t)ks * KC * NO; }
    else          { xs = inT2 + (size_t)(ks - SK1) * KC * 64; wb = WT2 + (size_t)(ks - SK1) * KC * NO; }
    const float* wp = wb + nb;
    const float* xp = xs + lane;

    float acc[32];
    #pragma unroll
    for (int j = 0; j < 32; ++j) acc[j] = 0.f;
    float x0 = xp[0], x1 = xp[64], x2 = xp[128], x3 = xp[192];
    for (int k = 0; k < KC; k += 4) {
        float xn0 = 0.f, xn1 = 0.f, xn2 = 0.f, xn3 = 0.f;
        if (k + 4 < KC) {
            xn0 = xp[(k + 4) * 64];
            xn1 = xp[(k + 5) * 64];
            xn2 = xp[(k + 6) * 64];
            xn3 = xp[(k + 7) * 64];
        }
        #pragma unroll
        for (int j = 0; j < 32; ++j) acc[j] = fmaf(x0, wp[(size_t)(k + 0) * NO + j], acc[j]);
        #pragma unroll
        for (int j = 0; j < 32; ++j) acc[j] = fmaf(x1, wp[(size_t)(k + 1) * NO + j], acc[j]);
        #pragma unroll
        for (int j = 0; j < 32; ++j) acc[j] = fmaf(x2, wp[(size_t)(k + 2) * NO + j], acc[j]);
        #pragma unroll
        for (int j = 0; j < 32; ++j) acc[j] = fmaf(x3, wp[(size_t)(k + 3) * NO + j], acc[j]);
        x0 = xn0; x1 = xn1; x2 = xn2; x3 = xn3;
    }
    float* pp = P + ((size_t)ks * NO + nb) * 64 + lane;
    #pragma unroll
    for (int j = 0; j < 32; ++j) pp[j * 64] = acc[j];

    if (aT) {
        __threadfence();
        __syncthreads();
        if (threadIdx.x == 0) last = atomicAdd(&counters[blockIdx.x], 1u);
        __syncthreads();
        if (last == gridDim.y - 1) {
            if (threadIdx.x == 0) counters[blockIdx.x] = 0u;   // self-clean
            __threadfence();
            int SKt = gridDim.y;
            int base_n = blockIdx.x * 128;
            for (int idx = threadIdx.x; idx < 2048; idx += 256) {
                int nloc = idx >> 4;
                int m4 = (idx & 15) << 2;
                int n = base_n + nloc;
                size_t off = (size_t)n * 64 + m4;
                float b0 = bias[n];
                float4 s = make_float4(b0, b0, b0, b0);
                for (int k2 = 0; k2 < SKt; ++k2) {
                    float4 v = *(const float4*)&P[(size_t)k2 * NO * 64 + off];
                    s.x += v.x; s.y += v.y; s.z += v.z; s.w += v.w;
                }
                if (relu) {
                    s.x = fmaxf(s.x, 0.f); s.y = fmaxf(s.y, 0.f);
                    s.z = fmaxf(s.z, 0.f); s.w = fmaxf(s.w, 0.f);
                }
                *(float4*)&aT[off] = s;
                if (a_std) {
                    a_std[(size_t)(m4 + 0) * NO + n] = s.x;
                    a_std[(size_t)(m4 + 1) * NO + n] = s.y;
                    a_std[(size_t)(m4 + 2) * NO + n] = s.z;
                    a_std[(size_t)(m4 + 3) * NO + n] = s.w;
                }
            }
        }
    }
}

// ==================== LSTM pointwise from 9 partials ====================
__global__ void lstm_update2(const float* __restrict__ P,
                             const float* __restrict__ b_ih, const float* __restrict__ b_hh,
                             float* __restrict__ hT, float* __restrict__ cT) {
    int t = blockIdx.x * blockDim.x + threadIdx.x;
    if (t >= HDIM * BSZ) return;
    int j = t >> 6, b = t & 63;
    float g4[4];
    #pragma unroll
    for (int gi = 0; gi < 4; ++gi) {
        int row = gi * HDIM + j;
        float v = b_ih[row] + b_hh[row];
        size_t base = (size_t)row * 64 + b;
        #pragma unroll
        for (int ks = 0; ks < 9; ++ks) v += P[(size_t)ks * 4096 * 64 + base];
        g4[gi] = v;
    }
    float si = 1.f / (1.f + expf(-g4[0]));
    float sf = 1.f / (1.f + expf(-g4[1]));
    float gg = tanhf(g4[2]);
    float so = 1.f / (1.f + expf(-g4[3]));
    float cn = sf * cT[t] + si * gg;
    cT[t] = cn;
    hT[t] = so * tanhf(cn);
}

// ==================== host ====================

extern "C" void kernel_launch(void* const* d_in, const int* in_sizes, int n_in,
                              void* d_out, int out_size, void* d_ws, size_t ws_size,
                              hipStream_t stream) {
    const float* feat   = (const float*)d_in[0];
    const int*   ei_in  = (const int*)d_in[1];
    const float* stats  = (const float*)d_in[4];
    const float* w_gcn  = (const float*)d_in[5];
    const float* b_gcn  = (const float*)d_in[6];
    const float* w_ih   = (const float*)d_in[7];
    const float* w_hh   = (const float*)d_in[8];
    const float* b_ih   = (const float*)d_in[9];
    const float* b_hh   = (const float*)d_in[10];
    const float* wm[6], *bm[6];
    for (int i = 0; i < 6; ++i) { wm[i] = (const float*)d_in[11 + 2*i]; bm[i] = (const float*)d_in[12 + 2*i]; }
    const int mlp_K[6]  = {1024, 2048, 4096, 2048, 1024, 512};
    const int mlp_NO[6] = {2048, 4096, 2048, 1024, 512, 128};

    float* out = (float*)d_out;
    float* ws  = (float*)d_ws;

    // ---------- workspace layout (floats) ----------
    size_t off = 0;
    unsigned int* counters = (unsigned int*)(ws); off += 64;
    float* wt_ih = ws + off; off += (size_t)128 * 4096;
    float* wt_hh = ws + off; off += (size_t)1024 * 4096;
    float* wt[6];
    const size_t wt_sz[6] = {(size_t)1024*2048, (size_t)2048*4096, (size_t)4096*2048,
                             (size_t)2048*1024, (size_t)1024*512, (size_t)512*128};
    for (int i = 0; i < 6; ++i) { wt[i] = ws + off; off += wt_sz[i]; }
    float* P_sh   = ws + off; off += (size_t)9 * 4096 * 64;   // shared partials (lstm & mlp)
    float* gT_all = ws + off; off += (size_t)10 * 128 * 64;
    float* gT_dec = ws + off; off += 8192;
    float* hT     = ws + off; off += 65536;
    float* cT     = ws + off; off += 65536;
    float* aT1    = ws + off; off += 131072;
    float* aT2    = ws + off; off += 262144;
    float* aT3    = ws + off; off += 131072;
    float* aT4    = ws + off; off += 65536;
    float* aT5    = ws + off; off += 32768;
    float* predT  = ws + off; off += 8192;
    float* deg    = ws + off; off += (size_t)10 * 4096;
    float* xw     = ws + off; off += (size_t)10 * 8192;
    size_t need_bytes = off * sizeof(float);
    if (ws_size < need_bytes) return;   // proven to fit per round-2 run; guard vs OOB

    // zero counters + LSTM state (hT,cT adjacent)
    hipMemsetAsync(counters, 0, 64 * sizeof(unsigned int), stream);
    hipMemsetAsync(hT, 0, 2 * 65536 * sizeof(float), stream);

    // frame 0 of output = feature_input[0]
    hipMemcpyAsync(out, feat, FRAME_ELEMS * sizeof(float), hipMemcpyDeviceToDevice, stream);

    // ---------- upfront: weight transposes ----------
    transpose_kernel<<<dim3(128 / 32, 4096 / 32), 256, 0, stream>>>(w_ih, wt_ih, 4096, 128);
    transpose_kernel<<<dim3(1024 / 32, 4096 / 32), 256, 0, stream>>>(w_hh, wt_hh, 4096, 1024);
    for (int l = 0; l < 6; ++l)
        transpose_kernel<<<dim3(mlp_K[l] / 32, mlp_NO[l] / 32), 256, 0, stream>>>(wm[l], wt[l], mlp_NO[l], mlp_K[l]);

    // ---------- upfront: batched GCN for all 10 input frames ----------
    bgcn_init_xw<<<10 * NTOT / 256, 256, 0, stream>>>(feat, w_gcn, deg, xw);
    bgcn_count<<<10 * NEDGE / 256, 256, 0, stream>>>(ei_in, deg);
    bgcn_node<<<10 * NTOT / 256, 256, 0, stream>>>(b_gcn, deg, xw, gT_all);
    bgcn_scatter<<<10 * NEDGE / 256, 256, 0, stream>>>(ei_in, deg, xw, gT_all);

    // ---------- 15 serial steps ----------
    // step s (0..14): input gT = gT_all frame s (s<=9) or gT_dec (s>=10, from
    // adjacency of pred frame s). Output frame s+1.
    for (int s = 0; s < 15; ++s) {
        const float* gT_s;
        if (s <= 9) {
            gT_s = gT_all + (size_t)s * 8192;
        } else {
            adj_gcn_kernel<<<BSZ, NN, 0, stream>>>(out + (size_t)s * FRAME_ELEMS, stats, w_gcn, b_gcn, gT_dec);
            gT_s = gT_dec;
        }
        // fused LSTM GEMM: ks 0..7 = hh chunks (K=1024), ks 8 = ih (K=128)
        gemm_cw3<128><<<dim3(32, 9), 256, 0, stream>>>(
            hT, gT_s, wt_hh, wt_ih, P_sh, nullptr, nullptr, nullptr, nullptr, 4096, 8, 0);
        lstm_update2<<<HDIM * BSZ / 256, 256, 0, stream>>>(P_sh, b_ih, b_hh, hT, cT);

        // MLP (reduce fused into gemm epilogue)
        float* frame = out + (size_t)(s + 1) * FRAME_ELEMS;
        // l1: K=1024 NO=2048  KC=64  SK=16
        gemm_cw3<64><<<dim3(16, 16), 256, 0, stream>>>(
            hT, nullptr, wt[0], nullptr, P_sh, bm[0], aT1, nullptr, counters, 2048, 16, 1);
        // l2: K=2048 NO=4096  KC=256 SK=8
        gemm_cw3<256><<<dim3(32, 8), 256, 0, stream>>>(
            aT1, nullptr, wt[1], nullptr, P_sh, bm[1], aT2, nullptr, counters, 4096, 8, 1);
        // l3: K=4096 NO=2048  KC=256 SK=16
        gemm_cw3<256><<<dim3(16, 16), 256, 0, stream>>>(
            aT2, nullptr, wt[2], nullptr, P_sh, bm[2], aT3, nullptr, counters, 2048, 16, 1);
        // l4: K=2048 NO=1024  KC=128 SK=16
        gemm_cw3<128><<<dim3(8, 16), 256, 0, stream>>>(
            aT3, nullptr, wt[3], nullptr, P_sh, bm[3], aT4, nullptr, counters, 1024, 16, 1);
        // l5: K=1024 NO=512   KC=64  SK=16
        gemm_cw3<64><<<dim3(4, 16), 256, 0, stream>>>(
            aT4, nullptr, wt[4], nullptr, P_sh, bm[4], aT5, nullptr, counters, 512, 16, 1);
        // l6: K=512  NO=128   KC=32  SK=16  (no relu; also write std-layout frame)
        gemm_cw3<32><<<dim3(1, 16), 256, 0, stream>>>(
            aT5, nullptr, wt[5], nullptr, P_sh, bm[5], predT, frame, counters, 128, 16, 0);
    }
}

// Round 4
// 4509.615 us; speedup vs baseline: 1.8318x; 1.8318x over previous
//
#include <hip/hip_runtime.h>
#include <hip/hip_bf16.h>
#include <math.h>

// Problem constants
#define NTOT 4096      // B*N nodes
#define NEDGE 65536    // E edges
#define BSZ 64         // batch
#define NN 64          // nodes per trajectory
#define HDIM 1024      // LSTM hidden
#define TIN 10
#define TOUT 6
#define FRAME_ELEMS (NTOT * 2)   // 8192 floats per frame

// ==================== weight transpose: W (NO,K) -> WT (K,NO) ====================
__global__ __launch_bounds__(256) void transpose_kernel(const float* __restrict__ W,
                                                        float* __restrict__ WT,
                                                        int NO, int K) {
    __shared__ float t[32][33];
    int k0 = blockIdx.x * 32;
    int n0 = blockIdx.y * 32;
    int tx = threadIdx.x & 31, ty = threadIdx.x >> 5;  // 32 x 8
    #pragma unroll
    for (int i = 0; i < 4; ++i)
        t[ty + i * 8][tx] = W[(size_t)(n0 + ty + i * 8) * K + k0 + tx];
    __syncthreads();
    #pragma unroll
    for (int i = 0; i < 4; ++i)
        WT[(size_t)(k0 + ty + i * 8) * NO + n0 + tx] = t[tx][ty + i * 8];
}

// ==================== batched GCN over 10 input frames ====================

__global__ void bgcn_init_xw(const float* __restrict__ feat, const float* __restrict__ wg,
                             float* __restrict__ deg, float* __restrict__ xw) {
    int i = blockIdx.x * blockDim.x + threadIdx.x;
    if (i >= 10 * NTOT) return;
    deg[i] = 1.0f;
    float x0 = feat[i * 2], x1 = feat[i * 2 + 1];
    xw[i * 2]     = x0 * wg[0] + x1 * wg[1];
    xw[i * 2 + 1] = x0 * wg[2] + x1 * wg[3];
}

__global__ void bgcn_count(const int* __restrict__ ei, float* __restrict__ deg) {
    int e = blockIdx.x * blockDim.x + threadIdx.x;
    if (e >= 10 * NEDGE) return;
    int t = e >> 16, el = e & 65535;
    int dst = ei[t * 2 * NEDGE + NEDGE + el];
    atomicAdd(&deg[t * NTOT + dst], 1.0f);
}

__global__ void bgcn_node(const float* __restrict__ bg, float* __restrict__ deg,
                          const float* __restrict__ xw, float* __restrict__ gT_all) {
    int i = blockIdx.x * blockDim.x + threadIdx.x;
    if (i >= 10 * NTOT) return;
    float dinv = rsqrtf(deg[i]);
    deg[i] = dinv;
    int t = i >> 12, node = i & 4095;
    int b = node >> 6, nn = node & 63;
    float w2 = dinv * dinv;
    gT_all[t * 8192 + (nn * 2 + 0) * 64 + b] = xw[i * 2]     * w2 + bg[0];
    gT_all[t * 8192 + (nn * 2 + 1) * 64 + b] = xw[i * 2 + 1] * w2 + bg[1];
}

__global__ void bgcn_scatter(const int* __restrict__ ei, const float* __restrict__ dinv,
                             const float* __restrict__ xw, float* __restrict__ gT_all) {
    int e = blockIdx.x * blockDim.x + threadIdx.x;
    if (e >= 10 * NEDGE) return;
    int t = e >> 16, el = e & 65535;
    int s = ei[t * 2 * NEDGE + el];
    int d = ei[t * 2 * NEDGE + NEDGE + el];
    float w = dinv[t * NTOT + s] * dinv[t * NTOT + d];
    int b = d >> 6, nn = d & 63;
    atomicAdd(&gT_all[t * 8192 + (nn * 2 + 0) * 64 + b], xw[(t * NTOT + s) * 2]     * w);
    atomicAdd(&gT_all[t * 8192 + (nn * 2 + 1) * 64 + b], xw[(t * NTOT + s) * 2 + 1] * w);
}

// ==================== fused adjacency + dense GCN (decoder) ====================
__global__ void adj_gcn_kernel(const float* __restrict__ pred,
                               const float* __restrict__ stats,
                               const float* __restrict__ wg,
                               const float* __restrict__ bg,
                               float* __restrict__ gT) {
    int b = blockIdx.x;
    int i = threadIdx.x;   // 64
    __shared__ float f0[NN], f1[NN], sxw0[NN], sxw1[NN], sdinv[NN];
    __shared__ int ex[NN];
    float p0 = pred[(b * NN + i) * 2], p1 = pred[(b * NN + i) * 2 + 1];
    float d0 = p0 * stats[0] + stats[2];
    float d1 = p1 * stats[1] + stats[3];
    f0[i] = d0; f1[i] = d1;
    ex[i] = (d0 > 0.04f) && (d1 > 0.04f);
    sxw0[i] = p0 * wg[0] + p1 * wg[1];
    sxw1[i] = p0 * wg[2] + p1 * wg[3];
    __syncthreads();
    float fi0 = f0[i], fi1 = f1[i];
    int exi = ex[i];
    float deg = 0.f;
    for (int j = 0; j < NN; ++j) {
        float dx = fi0 - f0[j], dy = fi1 - f1[j];
        float a = (i == j) ? 1.0f :
                  ((dx * dx + dy * dy <= 100.0f && exi && ex[j]) ? 1.0f : 0.0f);
        deg += a;
    }
    sdinv[i] = rsqrtf(deg);
    __syncthreads();
    float a0 = 0.f, a1 = 0.f;
    for (int j = 0; j < NN; ++j) {
        float dx = fi0 - f0[j], dy = fi1 - f1[j];
        float a = (i == j) ? 1.0f :
                  ((dx * dx + dy * dy <= 100.0f && exi && ex[j]) ? 1.0f : 0.0f);
        float an = a * sdinv[j];
        a0 += an * sxw0[j];
        a1 += an * sxw1[j];
    }
    float di = sdinv[i];
    gT[(i * 2 + 0) * 64 + b] = a0 * di + bg[0];
    gT[(i * 2 + 1) * 64 + b] = a1 * di + bg[1];
}

// ==================== broadcast-x GEMM ====================
// P[ks][n][m] = sum over k-chunk ks of in[m][k] * W[n][k].
// Thread <-> output column n (vector W loads, coalesced); x-chunk staged in
// LDS, read as wave-uniform broadcast; acc[64] = all batch rows.
// Split source: ks < SK1 reads inT/WT (chunk ks), else inT2/WT2 (chunk ks-SK1).
template<int KC>
__global__ __launch_bounds__(256) void gemm_bx(
    const float* __restrict__ inT, const float* __restrict__ inT2,
    const float* __restrict__ WT,  const float* __restrict__ WT2,
    float* __restrict__ P, int NO, int SK1)
{
    __shared__ float xs[KC * 64];
    int tid = threadIdx.x;
    int ks = blockIdx.y;
    const float* xsrc; const float* wsrc;
    if (ks < SK1) { xsrc = inT  + (size_t)ks * KC * 64;         wsrc = WT  + (size_t)ks * KC * NO; }
    else          { xsrc = inT2 + (size_t)(ks - SK1) * KC * 64; wsrc = WT2 + (size_t)(ks - SK1) * KC * NO; }
    for (int i = tid; i < KC * 16; i += blockDim.x)
        ((float4*)xs)[i] = ((const float4*)xsrc)[i];
    int n = blockIdx.x * blockDim.x + tid;
    const float* wp = wsrc + n;
    float acc[64];
    #pragma unroll
    for (int m = 0; m < 64; ++m) acc[m] = 0.f;
    __syncthreads();
    float wbuf[4];
    #pragma unroll
    for (int kk = 0; kk < 4; ++kk) wbuf[kk] = wp[(size_t)kk * NO];
    for (int k = 0; k < KC; k += 4) {
        float wn[4] = {0.f, 0.f, 0.f, 0.f};
        if (k + 4 < KC) {
            #pragma unroll
            for (int kk = 0; kk < 4; ++kk) wn[kk] = wp[(size_t)(k + 4 + kk) * NO];
        }
        #pragma unroll
        for (int kk = 0; kk < 4; ++kk) {
            const float* xrow = xs + (k + kk) * 64;
            float w = wbuf[kk];
            #pragma unroll
            for (int mq = 0; mq < 16; ++mq) {
                float4 xv = *(const float4*)(xrow + mq * 4);
                acc[mq * 4 + 0] = fmaf(w, xv.x, acc[mq * 4 + 0]);
                acc[mq * 4 + 1] = fmaf(w, xv.y, acc[mq * 4 + 1]);
                acc[mq * 4 + 2] = fmaf(w, xv.z, acc[mq * 4 + 2]);
                acc[mq * 4 + 3] = fmaf(w, xv.w, acc[mq * 4 + 3]);
            }
        }
        #pragma unroll
        for (int kk = 0; kk < 4; ++kk) wbuf[kk] = wn[kk];
    }
    float* pp = P + ((size_t)ks * NO + n) * 64;
    #pragma unroll
    for (int mq = 0; mq < 16; ++mq)
        *(float4*)(pp + mq * 4) = make_float4(acc[mq * 4], acc[mq * 4 + 1],
                                              acc[mq * 4 + 2], acc[mq * 4 + 3]);
}

// ==================== reduce partials + bias (+relu) ====================
__global__ void reduce_relu_kernel(const float* __restrict__ P,
                                   const float* __restrict__ bias,
                                   float* __restrict__ aT,
                                   float* __restrict__ a_std,
                                   int NO, int SK, int relu) {
    int idx = blockIdx.x * blockDim.x + threadIdx.x;
    if (idx >= NO * 64) return;
    int n = idx >> 6, m = idx & 63;
    float v = bias[n];
    for (int ks = 0; ks < SK; ++ks) v += P[(size_t)ks * NO * 64 + idx];
    if (relu) v = fmaxf(v, 0.f);
    aT[idx] = v;
    if (a_std) a_std[(size_t)m * NO + n] = v;
}

// ==================== LSTM pointwise from 9 partials ====================
__global__ void lstm_update2(const float* __restrict__ P,
                             const float* __restrict__ b_ih, const float* __restrict__ b_hh,
                             float* __restrict__ hT, float* __restrict__ cT) {
    int t = blockIdx.x * blockDim.x + threadIdx.x;
    if (t >= HDIM * BSZ) return;
    int j = t >> 6, b = t & 63;
    float g4[4];
    #pragma unroll
    for (int gi = 0; gi < 4; ++gi) {
        int row = gi * HDIM + j;
        float v = b_ih[row] + b_hh[row];
        size_t base = (size_t)row * 64 + b;
        #pragma unroll
        for (int ks = 0; ks < 9; ++ks) v += P[(size_t)ks * 4096 * 64 + base];
        g4[gi] = v;
    }
    float si = 1.f / (1.f + expf(-g4[0]));
    float sf = 1.f / (1.f + expf(-g4[1]));
    float gg = tanhf(g4[2]);
    float so = 1.f / (1.f + expf(-g4[3]));
    float cn = sf * cT[t] + si * gg;
    cT[t] = cn;
    hT[t] = so * tanhf(cn);
}

// ==================== host ====================

extern "C" void kernel_launch(void* const* d_in, const int* in_sizes, int n_in,
                              void* d_out, int out_size, void* d_ws, size_t ws_size,
                              hipStream_t stream) {
    const float* feat   = (const float*)d_in[0];
    const int*   ei_in  = (const int*)d_in[1];
    const float* stats  = (const float*)d_in[4];
    const float* w_gcn  = (const float*)d_in[5];
    const float* b_gcn  = (const float*)d_in[6];
    const float* w_ih   = (const float*)d_in[7];
    const float* w_hh   = (const float*)d_in[8];
    const float* b_ih   = (const float*)d_in[9];
    const float* b_hh   = (const float*)d_in[10];
    const float* wm[6], *bm[6];
    for (int i = 0; i < 6; ++i) { wm[i] = (const float*)d_in[11 + 2*i]; bm[i] = (const float*)d_in[12 + 2*i]; }
    const int mlp_K[6]  = {1024, 2048, 4096, 2048, 1024, 512};
    const int mlp_NO[6] = {2048, 4096, 2048, 1024, 512, 128};

    float* out = (float*)d_out;
    float* ws  = (float*)d_ws;

    // ---------- workspace layout (floats) ----------
    size_t off = 0;
    float* wt_ih = ws + off; off += (size_t)128 * 4096;
    float* wt_hh = ws + off; off += (size_t)1024 * 4096;
    float* wt[6];
    const size_t wt_sz[6] = {(size_t)1024*2048, (size_t)2048*4096, (size_t)4096*2048,
                             (size_t)2048*1024, (size_t)1024*512, (size_t)512*128};
    for (int i = 0; i < 6; ++i) { wt[i] = ws + off; off += wt_sz[i]; }
    float* P      = ws + off; off += (size_t)32 * 2048 * 64;  // 4.19M floats (max of all SK*NO)
    float* gT_all = ws + off; off += (size_t)10 * 128 * 64;
    float* gT_dec = ws + off; off += 8192;
    float* hT     = ws + off; off += 65536;
    float* cT     = ws + off; off += 65536;
    float* aT1    = ws + off; off += 131072;
    float* aT2    = ws + off; off += 262144;
    float* aT3    = ws + off; off += 131072;
    float* aT4    = ws + off; off += 65536;
    float* aT5    = ws + off; off += 32768;
    float* predT  = ws + off; off += 8192;
    float* deg    = ws + off; off += (size_t)10 * 4096;
    float* xw     = ws + off; off += (size_t)10 * 8192;
    size_t need_bytes = off * sizeof(float);
    if (ws_size < need_bytes) return;

    hipMemsetAsync(hT, 0, 2 * 65536 * sizeof(float), stream);
    hipMemcpyAsync(out, feat, FRAME_ELEMS * sizeof(float), hipMemcpyDeviceToDevice, stream);

    // ---------- upfront: weight transposes ----------
    transpose_kernel<<<dim3(128 / 32, 4096 / 32), 256, 0, stream>>>(w_ih, wt_ih, 4096, 128);
    transpose_kernel<<<dim3(1024 / 32, 4096 / 32), 256, 0, stream>>>(w_hh, wt_hh, 4096, 1024);
    for (int l = 0; l < 6; ++l)
        transpose_kernel<<<dim3(mlp_K[l] / 32, mlp_NO[l] / 32), 256, 0, stream>>>(wm[l], wt[l], mlp_NO[l], mlp_K[l]);

    // ---------- upfront: batched GCN for all 10 input frames ----------
    bgcn_init_xw<<<10 * NTOT / 256, 256, 0, stream>>>(feat, w_gcn, deg, xw);
    bgcn_count<<<10 * NEDGE / 256, 256, 0, stream>>>(ei_in, deg);
    bgcn_node<<<10 * NTOT / 256, 256, 0, stream>>>(b_gcn, deg, xw, gT_all);
    bgcn_scatter<<<10 * NEDGE / 256, 256, 0, stream>>>(ei_in, deg, xw, gT_all);

    // ---------- 15 serial steps ----------
    for (int s = 0; s < 15; ++s) {
        const float* gT_s;
        if (s <= 9) {
            gT_s = gT_all + (size_t)s * 8192;
        } else {
            adj_gcn_kernel<<<BSZ, NN, 0, stream>>>(out + (size_t)s * FRAME_ELEMS, stats, w_gcn, b_gcn, gT_dec);
            gT_s = gT_dec;
        }
        // LSTM: ks 0..7 = hh chunks (K=1024, KC=128), ks 8 = ih (K=128)
        gemm_bx<128><<<dim3(16, 9), 256, 0, stream>>>(hT, gT_s, wt_hh, wt_ih, P, 4096, 8);
        lstm_update2<<<HDIM * BSZ / 256, 256, 0, stream>>>(P, b_ih, b_hh, hT, cT);

        float* frame = out + (size_t)(s + 1) * FRAME_ELEMS;
        // l1: K=1024 NO=2048  KC=64  SK=16
        gemm_bx<64><<<dim3(8, 16), 256, 0, stream>>>(hT, nullptr, wt[0], nullptr, P, 2048, 16);
        reduce_relu_kernel<<<2048 * 64 / 256, 256, 0, stream>>>(P, bm[0], aT1, nullptr, 2048, 16, 1);
        // l2: K=2048 NO=4096  KC=128 SK=16
        gemm_bx<128><<<dim3(16, 16), 256, 0, stream>>>(aT1, nullptr, wt[1], nullptr, P, 4096, 16);
        reduce_relu_kernel<<<4096 * 64 / 256, 256, 0, stream>>>(P, bm[1], aT2, nullptr, 4096, 16, 1);
        // l3: K=4096 NO=2048  KC=128 SK=32
        gemm_bx<128><<<dim3(8, 32), 256, 0, stream>>>(aT2, nullptr, wt[2], nullptr, P, 2048, 32);
        reduce_relu_kernel<<<2048 * 64 / 256, 256, 0, stream>>>(P, bm[2], aT3, nullptr, 2048, 32, 1);
        // l4: K=2048 NO=1024  KC=64  SK=32
        gemm_bx<64><<<dim3(4, 32), 256, 0, stream>>>(aT3, nullptr, wt[3], nullptr, P, 1024, 32);
        reduce_relu_kernel<<<1024 * 64 / 256, 256, 0, stream>>>(P, bm[3], aT4, nullptr, 1024, 32, 1);
        // l5: K=1024 NO=512   KC=64  SK=16
        gemm_bx<64><<<dim3(2, 16), 256, 0, stream>>>(aT4, nullptr, wt[4], nullptr, P, 512, 16);
        reduce_relu_kernel<<<512 * 64 / 256, 256, 0, stream>>>(P, bm[4], aT5, nullptr, 512, 16, 1);
        // l6: K=512  NO=128   KC=64  SK=8   (128-thread blocks; also write std frame)
        gemm_bx<64><<<dim3(1, 8), 128, 0, stream>>>(aT5, nullptr, wt[5], nullptr, P, 128, 8);
        reduce_relu_kernel<<<128 * 64 / 256, 256, 0, stream>>>(P, bm[5], predT, frame, 128, 8, 0);
    }
}

// Round 5
// 2745.634 us; speedup vs baseline: 3.0086x; 1.6425x over previous
//
#include <hip/hip_runtime.h>
#include <hip/hip_bf16.h>
#include <math.h>

// Problem constants
#define NTOT 4096      // B*N nodes
#define NEDGE 65536    // E edges
#define BSZ 64         // batch
#define NN 64          // nodes per trajectory
#define HDIM 1024      // LSTM hidden
#define TIN 10
#define TOUT 6
#define FRAME_ELEMS (NTOT * 2)   // 8192 floats per frame

// ==================== weight transpose: W (NO,K) -> WT (K,NO) ====================
__global__ __launch_bounds__(256) void transpose_kernel(const float* __restrict__ W,
                                                        float* __restrict__ WT,
                                                        int NO, int K) {
    __shared__ float t[32][33];
    int k0 = blockIdx.x * 32;
    int n0 = blockIdx.y * 32;
    int tx = threadIdx.x & 31, ty = threadIdx.x >> 5;  // 32 x 8
    #pragma unroll
    for (int i = 0; i < 4; ++i)
        t[ty + i * 8][tx] = W[(size_t)(n0 + ty + i * 8) * K + k0 + tx];
    __syncthreads();
    #pragma unroll
    for (int i = 0; i < 4; ++i)
        WT[(size_t)(k0 + ty + i * 8) * NO + n0 + tx] = t[tx][ty + i * 8];
}

// ==================== batched GCN over 10 input frames ====================

__global__ void bgcn_init_xw(const float* __restrict__ feat, const float* __restrict__ wg,
                             float* __restrict__ deg, float* __restrict__ xw) {
    int i = blockIdx.x * blockDim.x + threadIdx.x;
    if (i >= 10 * NTOT) return;
    deg[i] = 1.0f;
    float x0 = feat[i * 2], x1 = feat[i * 2 + 1];
    xw[i * 2]     = x0 * wg[0] + x1 * wg[1];
    xw[i * 2 + 1] = x0 * wg[2] + x1 * wg[3];
}

__global__ void bgcn_count(const int* __restrict__ ei, float* __restrict__ deg) {
    int e = blockIdx.x * blockDim.x + threadIdx.x;
    if (e >= 10 * NEDGE) return;
    int t = e >> 16, el = e & 65535;
    int dst = ei[t * 2 * NEDGE + NEDGE + el];
    atomicAdd(&deg[t * NTOT + dst], 1.0f);
}

__global__ void bgcn_node(const float* __restrict__ bg, float* __restrict__ deg,
                          const float* __restrict__ xw, float* __restrict__ gT_all) {
    int i = blockIdx.x * blockDim.x + threadIdx.x;
    if (i >= 10 * NTOT) return;
    float dinv = rsqrtf(deg[i]);
    deg[i] = dinv;
    int t = i >> 12, node = i & 4095;
    int b = node >> 6, nn = node & 63;
    float w2 = dinv * dinv;
    gT_all[t * 8192 + (nn * 2 + 0) * 64 + b] = xw[i * 2]     * w2 + bg[0];
    gT_all[t * 8192 + (nn * 2 + 1) * 64 + b] = xw[i * 2 + 1] * w2 + bg[1];
}

__global__ void bgcn_scatter(const int* __restrict__ ei, const float* __restrict__ dinv,
                             const float* __restrict__ xw, float* __restrict__ gT_all) {
    int e = blockIdx.x * blockDim.x + threadIdx.x;
    if (e >= 10 * NEDGE) return;
    int t = e >> 16, el = e & 65535;
    int s = ei[t * 2 * NEDGE + el];
    int d = ei[t * 2 * NEDGE + NEDGE + el];
    float w = dinv[t * NTOT + s] * dinv[t * NTOT + d];
    int b = d >> 6, nn = d & 63;
    atomicAdd(&gT_all[t * 8192 + (nn * 2 + 0) * 64 + b], xw[(t * NTOT + s) * 2]     * w);
    atomicAdd(&gT_all[t * 8192 + (nn * 2 + 1) * 64 + b], xw[(t * NTOT + s) * 2 + 1] * w);
}

// ==================== broadcast-x GEMM, 16 m per thread ====================
// P[ks][n][m] = sum over k-chunk ks of in[m][k] * W[n][k].
// thread = (n_local = tid>>2, q = tid&3); acc[16] covers m in [q*16, q*16+16).
// x-chunk staged in LDS (broadcast reads); W streamed via coalesced vector loads.
// Split source: ks < SK1 reads inT/WT (chunk ks), else inT2/WT2 (chunk ks-SK1).
template<int KC>
__global__ __launch_bounds__(256) void gemm_bx2(
    const float* __restrict__ inT, const float* __restrict__ inT2,
    const float* __restrict__ WT,  const float* __restrict__ WT2,
    float* __restrict__ P, int NO, int SK1)
{
    __shared__ float xs[KC * 64];
    int tid = threadIdx.x;
    int ks = blockIdx.y;
    const float* xsrc; const float* wsrc;
    if (ks < SK1) { xsrc = inT  + (size_t)ks * KC * 64;         wsrc = WT  + (size_t)ks * KC * NO; }
    else          { xsrc = inT2 + (size_t)(ks - SK1) * KC * 64; wsrc = WT2 + (size_t)(ks - SK1) * KC * NO; }
    for (int i = tid; i < KC * 16; i += 256)
        ((float4*)xs)[i] = ((const float4*)xsrc)[i];
    int nl = tid >> 2, q = tid & 3;
    int n = blockIdx.x * 64 + nl;
    const float* wp = wsrc + n;
    const float* xq = xs + q * 16;
    float acc[16];
    #pragma unroll
    for (int j = 0; j < 16; ++j) acc[j] = 0.f;
    __syncthreads();
    float wbuf[4];
    #pragma unroll
    for (int kk = 0; kk < 4; ++kk) wbuf[kk] = wp[(size_t)kk * NO];
    for (int k = 0; k < KC; k += 4) {
        float wn[4] = {0.f, 0.f, 0.f, 0.f};
        if (k + 4 < KC) {
            #pragma unroll
            for (int kk = 0; kk < 4; ++kk) wn[kk] = wp[(size_t)(k + 4 + kk) * NO];
        }
        #pragma unroll
        for (int kk = 0; kk < 4; ++kk) {
            const float* xrow = xq + (k + kk) * 64;
            float w = wbuf[kk];
            float4 x0 = *(const float4*)(xrow + 0);
            float4 x1 = *(const float4*)(xrow + 4);
            float4 x2 = *(const float4*)(xrow + 8);
            float4 x3 = *(const float4*)(xrow + 12);
            acc[0]  = fmaf(w, x0.x, acc[0]);  acc[1]  = fmaf(w, x0.y, acc[1]);
            acc[2]  = fmaf(w, x0.z, acc[2]);  acc[3]  = fmaf(w, x0.w, acc[3]);
            acc[4]  = fmaf(w, x1.x, acc[4]);  acc[5]  = fmaf(w, x1.y, acc[5]);
            acc[6]  = fmaf(w, x1.z, acc[6]);  acc[7]  = fmaf(w, x1.w, acc[7]);
            acc[8]  = fmaf(w, x2.x, acc[8]);  acc[9]  = fmaf(w, x2.y, acc[9]);
            acc[10] = fmaf(w, x2.z, acc[10]); acc[11] = fmaf(w, x2.w, acc[11]);
            acc[12] = fmaf(w, x3.x, acc[12]); acc[13] = fmaf(w, x3.y, acc[13]);
            acc[14] = fmaf(w, x3.z, acc[14]); acc[15] = fmaf(w, x3.w, acc[15]);
        }
        #pragma unroll
        for (int kk = 0; kk < 4; ++kk) wbuf[kk] = wn[kk];
    }
    float* pp = P + ((size_t)ks * NO + n) * 64 + q * 16;
    *(float4*)(pp + 0)  = make_float4(acc[0],  acc[1],  acc[2],  acc[3]);
    *(float4*)(pp + 4)  = make_float4(acc[4],  acc[5],  acc[6],  acc[7]);
    *(float4*)(pp + 8)  = make_float4(acc[8],  acc[9],  acc[10], acc[11]);
    *(float4*)(pp + 12) = make_float4(acc[12], acc[13], acc[14], acc[15]);
}

// ==================== reduce partials + bias (+relu) -> aT (NO,64) ====================
__global__ void reduce_relu_kernel(const float* __restrict__ P,
                                   const float* __restrict__ bias,
                                   float* __restrict__ aT,
                                   int NO, int SK, int relu) {
    int idx = blockIdx.x * blockDim.x + threadIdx.x;
    if (idx >= NO * 64) return;
    int n = idx >> 6;
    float v = bias[n];
    for (int ks = 0; ks < SK; ++ks) v += P[(size_t)ks * NO * 64 + idx];
    if (relu) v = fmaxf(v, 0.f);
    aT[idx] = v;
}

// ==================== LSTM pointwise from 9 partials ====================
__global__ void lstm_update2(const float* __restrict__ P,
                             const float* __restrict__ b_ih, const float* __restrict__ b_hh,
                             float* __restrict__ hT, float* __restrict__ cT) {
    int t = blockIdx.x * blockDim.x + threadIdx.x;
    if (t >= HDIM * BSZ) return;
    int j = t >> 6, b = t & 63;
    float g4[4];
    #pragma unroll
    for (int gi = 0; gi < 4; ++gi) {
        int row = gi * HDIM + j;
        float v = b_ih[row] + b_hh[row];
        size_t base = (size_t)row * 64 + b;
        #pragma unroll
        for (int ks = 0; ks < 9; ++ks) v += P[(size_t)ks * 4096 * 64 + base];
        g4[gi] = v;
    }
    float si = 1.f / (1.f + expf(-g4[0]));
    float sf = 1.f / (1.f + expf(-g4[1]));
    float gg = tanhf(g4[2]);
    float so = 1.f / (1.f + expf(-g4[3]));
    float cn = sf * cT[t] + si * gg;
    cT[t] = cn;
    hT[t] = so * tanhf(cn);
}

// ==================== l6 finalize: reduce+bias -> frame (std layout) ====================
// P: (SK, 128, 64). block = trajectory b (64 blocks), thread = n (0..127).
__global__ void finalize_enc(const float* __restrict__ P, const float* __restrict__ bias,
                             float* __restrict__ frame, int SK) {
    int b = blockIdx.x;
    int n = threadIdx.x;
    float v = bias[n];
    for (int ks = 0; ks < SK; ++ks) v += P[((size_t)ks * 128 + n) * 64 + b];
    frame[b * 128 + n] = v;
}

// decoder variant: also builds adjacency + dense GCN -> gT_dec (128,64)
__global__ void finalize_dec(const float* __restrict__ P, const float* __restrict__ bias,
                             const float* __restrict__ stats,
                             const float* __restrict__ wg, const float* __restrict__ bg,
                             float* __restrict__ frame, float* __restrict__ gT, int SK) {
    int b = blockIdx.x;
    int n = threadIdx.x;   // 0..127
    __shared__ float p[128];
    __shared__ float f0[NN], f1[NN], sxw0[NN], sxw1[NN], sdinv[NN];
    __shared__ int ex[NN];
    float v = bias[n];
    for (int ks = 0; ks < SK; ++ks) v += P[((size_t)ks * 128 + n) * 64 + b];
    p[n] = v;
    frame[b * 128 + n] = v;
    __syncthreads();
    int i = n;
    if (i < NN) {
        float p0 = p[i * 2], p1 = p[i * 2 + 1];
        float d0 = p0 * stats[0] + stats[2];
        float d1 = p1 * stats[1] + stats[3];
        f0[i] = d0; f1[i] = d1;
        ex[i] = (d0 > 0.04f) && (d1 > 0.04f);
        sxw0[i] = p0 * wg[0] + p1 * wg[1];
        sxw1[i] = p0 * wg[2] + p1 * wg[3];
    }
    __syncthreads();
    if (i < NN) {
        float fi0 = f0[i], fi1 = f1[i];
        int exi = ex[i];
        float deg = 0.f;
        for (int j = 0; j < NN; ++j) {
            float dx = fi0 - f0[j], dy = fi1 - f1[j];
            float a = (i == j) ? 1.0f :
                      ((dx * dx + dy * dy <= 100.0f && exi && ex[j]) ? 1.0f : 0.0f);
            deg += a;
        }
        sdinv[i] = rsqrtf(deg);
    }
    __syncthreads();
    if (i < NN) {
        float fi0 = f0[i], fi1 = f1[i];
        int exi = ex[i];
        float a0 = 0.f, a1 = 0.f;
        for (int j = 0; j < NN; ++j) {
            float dx = fi0 - f0[j], dy = fi1 - f1[j];
            float a = (i == j) ? 1.0f :
                      ((dx * dx + dy * dy <= 100.0f && exi && ex[j]) ? 1.0f : 0.0f);
            float an = a * sdinv[j];
            a0 += an * sxw0[j];
            a1 += an * sxw1[j];
        }
        float di = sdinv[i];
        gT[(i * 2 + 0) * 64 + b] = a0 * di + bg[0];
        gT[(i * 2 + 1) * 64 + b] = a1 * di + bg[1];
    }
}

// ==================== host ====================

extern "C" void kernel_launch(void* const* d_in, const int* in_sizes, int n_in,
                              void* d_out, int out_size, void* d_ws, size_t ws_size,
                              hipStream_t stream) {
    const float* feat   = (const float*)d_in[0];
    const int*   ei_in  = (const int*)d_in[1];
    const float* stats  = (const float*)d_in[4];
    const float* w_gcn  = (const float*)d_in[5];
    const float* b_gcn  = (const float*)d_in[6];
    const float* w_ih   = (const float*)d_in[7];
    const float* w_hh   = (const float*)d_in[8];
    const float* b_ih   = (const float*)d_in[9];
    const float* b_hh   = (const float*)d_in[10];
    const float* wm[6], *bm[6];
    for (int i = 0; i < 6; ++i) { wm[i] = (const float*)d_in[11 + 2*i]; bm[i] = (const float*)d_in[12 + 2*i]; }
    const int mlp_K[6]  = {1024, 2048, 4096, 2048, 1024, 512};
    const int mlp_NO[6] = {2048, 4096, 2048, 1024, 512, 128};

    float* out = (float*)d_out;
    float* ws  = (float*)d_ws;

    // ---------- workspace layout (floats) ----------
    size_t off = 0;
    float* wt_ih = ws + off; off += (size_t)128 * 4096;
    float* wt_hh = ws + off; off += (size_t)1024 * 4096;
    float* wt[6];
    const size_t wt_sz[6] = {(size_t)1024*2048, (size_t)2048*4096, (size_t)4096*2048,
                             (size_t)2048*1024, (size_t)1024*512, (size_t)512*128};
    for (int i = 0; i < 6; ++i) { wt[i] = ws + off; off += wt_sz[i]; }
    float* P      = ws + off; off += (size_t)16 * 4096 * 64;  // 4.19M floats (max SK*NO*64)
    float* gT_all = ws + off; off += (size_t)10 * 128 * 64;
    float* gT_dec = ws + off; off += 8192;
    float* hT     = ws + off; off += 65536;
    float* cT     = ws + off; off += 65536;
    float* aT1    = ws + off; off += 131072;
    float* aT2    = ws + off; off += 262144;
    float* aT3    = ws + off; off += 131072;
    float* aT4    = ws + off; off += 65536;
    float* aT5    = ws + off; off += 32768;
    float* deg    = ws + off; off += (size_t)10 * 4096;
    float* xw     = ws + off; off += (size_t)10 * 8192;
    size_t need_bytes = off * sizeof(float);
    if (ws_size < need_bytes) return;

    hipMemsetAsync(hT, 0, 2 * 65536 * sizeof(float), stream);
    hipMemcpyAsync(out, feat, FRAME_ELEMS * sizeof(float), hipMemcpyDeviceToDevice, stream);

    // ---------- upfront: weight transposes ----------
    transpose_kernel<<<dim3(128 / 32, 4096 / 32), 256, 0, stream>>>(w_ih, wt_ih, 4096, 128);
    transpose_kernel<<<dim3(1024 / 32, 4096 / 32), 256, 0, stream>>>(w_hh, wt_hh, 4096, 1024);
    for (int l = 0; l < 6; ++l)
        transpose_kernel<<<dim3(mlp_K[l] / 32, mlp_NO[l] / 32), 256, 0, stream>>>(wm[l], wt[l], mlp_NO[l], mlp_K[l]);

    // ---------- upfront: batched GCN for all 10 input frames ----------
    bgcn_init_xw<<<10 * NTOT / 256, 256, 0, stream>>>(feat, w_gcn, deg, xw);
    bgcn_count<<<10 * NEDGE / 256, 256, 0, stream>>>(ei_in, deg);
    bgcn_node<<<10 * NTOT / 256, 256, 0, stream>>>(b_gcn, deg, xw, gT_all);
    bgcn_scatter<<<10 * NEDGE / 256, 256, 0, stream>>>(ei_in, deg, xw, gT_all);

    // ---------- 15 serial steps ----------
    for (int s = 0; s < 15; ++s) {
        const float* gT_s = (s <= 9) ? (gT_all + (size_t)s * 8192) : gT_dec;

        // LSTM: ks 0..7 = hh chunks (K=1024, KC=128), ks 8 = ih (K=128)
        gemm_bx2<128><<<dim3(64, 9), 256, 0, stream>>>(hT, gT_s, wt_hh, wt_ih, P, 4096, 8);
        lstm_update2<<<HDIM * BSZ / 256, 256, 0, stream>>>(P, b_ih, b_hh, hT, cT);

        float* frame = out + (size_t)(s + 1) * FRAME_ELEMS;
        // l1: K=1024 NO=2048  KC=64  SK=16
        gemm_bx2<64><<<dim3(32, 16), 256, 0, stream>>>(hT, nullptr, wt[0], nullptr, P, 2048, 16);
        reduce_relu_kernel<<<2048 * 64 / 256, 256, 0, stream>>>(P, bm[0], aT1, 2048, 16, 1);
        // l2: K=2048 NO=4096  KC=128 SK=16
        gemm_bx2<128><<<dim3(64, 16), 256, 0, stream>>>(aT1, nullptr, wt[1], nullptr, P, 4096, 16);
        reduce_relu_kernel<<<4096 * 64 / 256, 256, 0, stream>>>(P, bm[1], aT2, 4096, 16, 1);
        // l3: K=4096 NO=2048  KC=128 SK=32
        gemm_bx2<128><<<dim3(32, 32), 256, 0, stream>>>(aT2, nullptr, wt[2], nullptr, P, 2048, 32);
        reduce_relu_kernel<<<2048 * 64 / 256, 256, 0, stream>>>(P, bm[2], aT3, 2048, 32, 1);
        // l4: K=2048 NO=1024  KC=128 SK=16
        gemm_bx2<128><<<dim3(16, 16), 256, 0, stream>>>(aT3, nullptr, wt[3], nullptr, P, 1024, 16);
        reduce_relu_kernel<<<1024 * 64 / 256, 256, 0, stream>>>(P, bm[3], aT4, 1024, 16, 1);
        // l5: K=1024 NO=512   KC=64  SK=16
        gemm_bx2<64><<<dim3(8, 16), 256, 0, stream>>>(aT4, nullptr, wt[4], nullptr, P, 512, 16);
        reduce_relu_kernel<<<512 * 64 / 256, 256, 0, stream>>>(P, bm[4], aT5, 512, 16, 1);
        // l6: K=512  NO=128   KC=64  SK=8 -> finalize (reduce+bias+frame[+adj+GCN])
        gemm_bx2<64><<<dim3(2, 8), 256, 0, stream>>>(aT5, nullptr, wt[5], nullptr, P, 128, 8);
        if (s >= 9 && s < 14) {
            finalize_dec<<<BSZ, 128, 0, stream>>>(P, bm[5], stats, w_gcn, b_gcn, frame, gT_dec, 8);
        } else {
            finalize_enc<<<BSZ, 128, 0, stream>>>(P, bm[5], frame, 8);
        }
    }
}

// Round 6
// 1827.609 us; speedup vs baseline: 4.5199x; 1.5023x over previous
//
#include <hip/hip_runtime.h>
#include <hip/hip_bf16.h>
#include <math.h>

// Problem constants
#define NTOT 4096      // B*N nodes
#define NEDGE 65536    // E edges
#define BSZ 64         // batch
#define NN 64          // nodes per trajectory
#define HDIM 1024      // LSTM hidden
#define TIN 10
#define TOUT 6
#define FRAME_ELEMS (NTOT * 2)   // 8192 floats per frame

typedef short s16x8 __attribute__((ext_vector_type(8)));
typedef float f32x4 __attribute__((ext_vector_type(4)));

__device__ __forceinline__ unsigned short f2bf(float f) {
    union { float f; unsigned u; } x; x.f = f;
    unsigned r = x.u + 0x7fffu + ((x.u >> 16) & 1u);
    return (unsigned short)(r >> 16);
}

// ==================== weight transpose: W (NO,K) -> WT (K,NO) ====================
__global__ __launch_bounds__(256) void transpose_kernel(const float* __restrict__ W,
                                                        float* __restrict__ WT,
                                                        int NO, int K) {
    __shared__ float t[32][33];
    int k0 = blockIdx.x * 32;
    int n0 = blockIdx.y * 32;
    int tx = threadIdx.x & 31, ty = threadIdx.x >> 5;  // 32 x 8
    #pragma unroll
    for (int i = 0; i < 4; ++i)
        t[ty + i * 8][tx] = W[(size_t)(n0 + ty + i * 8) * K + k0 + tx];
    __syncthreads();
    #pragma unroll
    for (int i = 0; i < 4; ++i)
        WT[(size_t)(k0 + ty + i * 8) * NO + n0 + tx] = t[tx][ty + i * 8];
}

// ==================== batched GCN over 10 input frames ====================

__global__ void bgcn_init_xw(const float* __restrict__ feat, const float* __restrict__ wg,
                             float* __restrict__ deg, float* __restrict__ xw) {
    int i = blockIdx.x * blockDim.x + threadIdx.x;
    if (i >= 10 * NTOT) return;
    deg[i] = 1.0f;
    float x0 = feat[i * 2], x1 = feat[i * 2 + 1];
    xw[i * 2]     = x0 * wg[0] + x1 * wg[1];
    xw[i * 2 + 1] = x0 * wg[2] + x1 * wg[3];
}

__global__ void bgcn_count(const int* __restrict__ ei, float* __restrict__ deg) {
    int e = blockIdx.x * blockDim.x + threadIdx.x;
    if (e >= 10 * NEDGE) return;
    int t = e >> 16, el = e & 65535;
    int dst = ei[t * 2 * NEDGE + NEDGE + el];
    atomicAdd(&deg[t * NTOT + dst], 1.0f);
}

__global__ void bgcn_node(const float* __restrict__ bg, float* __restrict__ deg,
                          const float* __restrict__ xw, float* __restrict__ gT_all) {
    int i = blockIdx.x * blockDim.x + threadIdx.x;
    if (i >= 10 * NTOT) return;
    float dinv = rsqrtf(deg[i]);
    deg[i] = dinv;
    int t = i >> 12, node = i & 4095;
    int b = node >> 6, nn = node & 63;
    float w2 = dinv * dinv;
    gT_all[t * 8192 + (nn * 2 + 0) * 64 + b] = xw[i * 2]     * w2 + bg[0];
    gT_all[t * 8192 + (nn * 2 + 1) * 64 + b] = xw[i * 2 + 1] * w2 + bg[1];
}

__global__ void bgcn_scatter(const int* __restrict__ ei, const float* __restrict__ dinv,
                             const float* __restrict__ xw, float* __restrict__ gT_all) {
    int e = blockIdx.x * blockDim.x + threadIdx.x;
    if (e >= 10 * NEDGE) return;
    int t = e >> 16, el = e & 65535;
    int s = ei[t * 2 * NEDGE + el];
    int d = ei[t * 2 * NEDGE + NEDGE + el];
    float w = dinv[t * NTOT + s] * dinv[t * NTOT + d];
    int b = d >> 6, nn = d & 63;
    atomicAdd(&gT_all[t * 8192 + (nn * 2 + 0) * 64 + b], xw[(t * NTOT + s) * 2]     * w);
    atomicAdd(&gT_all[t * 8192 + (nn * 2 + 1) * 64 + b], xw[(t * NTOT + s) * 2 + 1] * w);
}

// ==================== broadcast-x GEMM (staged KC, 16 m per thread) ====================
template<int KC>
__global__ __launch_bounds__(256) void gemm_bx3(
    const float* __restrict__ inT, const float* __restrict__ inT2,
    const float* __restrict__ WT,  const float* __restrict__ WT2,
    float* __restrict__ P, int NO, int SK1)
{
    constexpr int STG = (KC > 128) ? 128 : KC;
    __shared__ float xs[STG * 64];
    int tid = threadIdx.x;
    int ks = blockIdx.y;
    const float* xsrc; const float* wsrc;
    if (ks < SK1) { xsrc = inT  + (size_t)ks * KC * 64;         wsrc = WT  + (size_t)ks * KC * NO; }
    else          { xsrc = inT2 + (size_t)(ks - SK1) * KC * 64; wsrc = WT2 + (size_t)(ks - SK1) * KC * NO; }
    int nl = tid >> 2, q = tid & 3;
    int n = blockIdx.x * 64 + nl;
    const float* xq = xs + q * 16;
    float acc[16];
    #pragma unroll
    for (int j = 0; j < 16; ++j) acc[j] = 0.f;

    for (int kb = 0; kb < KC; kb += STG) {
        if (kb) __syncthreads();
        for (int i = tid; i < STG * 16; i += 256)
            ((float4*)xs)[i] = ((const float4*)(xsrc + (size_t)kb * 64))[i];
        __syncthreads();
        const float* wp = wsrc + (size_t)kb * NO + n;
        float wbuf[4];
        #pragma unroll
        for (int kk = 0; kk < 4; ++kk) wbuf[kk] = wp[(size_t)kk * NO];
        for (int k = 0; k < STG; k += 4) {
            float wn[4] = {0.f, 0.f, 0.f, 0.f};
            if (k + 4 < STG) {
                #pragma unroll
                for (int kk = 0; kk < 4; ++kk) wn[kk] = wp[(size_t)(k + 4 + kk) * NO];
            }
            #pragma unroll
            for (int kk = 0; kk < 4; ++kk) {
                const float* xrow = xq + (k + kk) * 64;
                float w = wbuf[kk];
                float4 x0 = *(const float4*)(xrow + 0);
                float4 x1 = *(const float4*)(xrow + 4);
                float4 x2 = *(const float4*)(xrow + 8);
                float4 x3 = *(const float4*)(xrow + 12);
                acc[0]  = fmaf(w, x0.x, acc[0]);  acc[1]  = fmaf(w, x0.y, acc[1]);
                acc[2]  = fmaf(w, x0.z, acc[2]);  acc[3]  = fmaf(w, x0.w, acc[3]);
                acc[4]  = fmaf(w, x1.x, acc[4]);  acc[5]  = fmaf(w, x1.y, acc[5]);
                acc[6]  = fmaf(w, x1.z, acc[6]);  acc[7]  = fmaf(w, x1.w, acc[7]);
                acc[8]  = fmaf(w, x2.x, acc[8]);  acc[9]  = fmaf(w, x2.y, acc[9]);
                acc[10] = fmaf(w, x2.z, acc[10]); acc[11] = fmaf(w, x2.w, acc[11]);
                acc[12] = fmaf(w, x3.x, acc[12]); acc[13] = fmaf(w, x3.y, acc[13]);
                acc[14] = fmaf(w, x3.z, acc[14]); acc[15] = fmaf(w, x3.w, acc[15]);
            }
            #pragma unroll
            for (int kk = 0; kk < 4; ++kk) wbuf[kk] = wn[kk];
        }
    }
    float* pp = P + ((size_t)ks * NO + n) * 64 + q * 16;
    *(float4*)(pp + 0)  = make_float4(acc[0],  acc[1],  acc[2],  acc[3]);
    *(float4*)(pp + 4)  = make_float4(acc[4],  acc[5],  acc[6],  acc[7]);
    *(float4*)(pp + 8)  = make_float4(acc[8],  acc[9],  acc[10], acc[11]);
    *(float4*)(pp + 12) = make_float4(acc[12], acc[13], acc[14], acc[15]);
}

// ==================== reduce partials + bias (+relu) -> aT (NO,64) ====================
__global__ void reduce_relu_kernel(const float* __restrict__ P,
                                   const float* __restrict__ bias,
                                   float* __restrict__ aT,
                                   int NO, int SK, int relu) {
    int idx = blockIdx.x * blockDim.x + threadIdx.x;
    if (idx >= NO * 64) return;
    int n = idx >> 6;
    float v = bias[n];
    for (int ks = 0; ks < SK; ++ks) v += P[(size_t)ks * NO * 64 + idx];
    if (relu) v = fmaxf(v, 0.f);
    aT[idx] = v;
}

// ==================== LSTM pointwise from 9 partials (+ optional bf16 h-stash) ====================
__global__ void lstm_update2(const float* __restrict__ P,
                             const float* __restrict__ b_ih, const float* __restrict__ b_hh,
                             float* __restrict__ hT, float* __restrict__ cT,
                             unsigned short* __restrict__ stash, int mbase) {
    int t = blockIdx.x * blockDim.x + threadIdx.x;
    if (t >= HDIM * BSZ) return;
    int j = t >> 6, b = t & 63;
    float g4[4];
    #pragma unroll
    for (int gi = 0; gi < 4; ++gi) {
        int row = gi * HDIM + j;
        float v = b_ih[row] + b_hh[row];
        size_t base = (size_t)row * 64 + b;
        #pragma unroll
        for (int ks = 0; ks < 9; ++ks) v += P[(size_t)ks * 4096 * 64 + base];
        g4[gi] = v;
    }
    float si = 1.f / (1.f + expf(-g4[0]));
    float sf = 1.f / (1.f + expf(-g4[1]));
    float gg = tanhf(g4[2]);
    float so = 1.f / (1.f + expf(-g4[3]));
    float cn = sf * cT[t] + si * gg;
    cT[t] = cn;
    float h = so * tanhf(cn);
    hT[t] = h;
    if (stash) stash[(size_t)(mbase + b) * HDIM + j] = f2bf(h);
}

// ==================== l6 finalize kernels (decoder path) ====================
__global__ void finalize_enc(const float* __restrict__ P, const float* __restrict__ bias,
                             float* __restrict__ frame, int SK) {
    int b = blockIdx.x;
    int n = threadIdx.x;
    float v = bias[n];
    for (int ks = 0; ks < SK; ++ks) v += P[((size_t)ks * 128 + n) * 64 + b];
    frame[b * 128 + n] = v;
}

__global__ void finalize_dec(const float* __restrict__ P, const float* __restrict__ bias,
                             const float* __restrict__ stats,
                             const float* __restrict__ wg, const float* __restrict__ bg,
                             float* __restrict__ frame, float* __restrict__ gT, int SK) {
    int b = blockIdx.x;
    int n = threadIdx.x;   // 0..127
    __shared__ float p[128];
    __shared__ float f0[NN], f1[NN], sxw0[NN], sxw1[NN], sdinv[NN];
    __shared__ int ex[NN];
    float v = bias[n];
    for (int ks = 0; ks < SK; ++ks) v += P[((size_t)ks * 128 + n) * 64 + b];
    p[n] = v;
    frame[b * 128 + n] = v;
    __syncthreads();
    int i = n;
    if (i < NN) {
        float p0 = p[i * 2], p1 = p[i * 2 + 1];
        float d0 = p0 * stats[0] + stats[2];
        float d1 = p1 * stats[1] + stats[3];
        f0[i] = d0; f1[i] = d1;
        ex[i] = (d0 > 0.04f) && (d1 > 0.04f);
        sxw0[i] = p0 * wg[0] + p1 * wg[1];
        sxw1[i] = p0 * wg[2] + p1 * wg[3];
    }
    __syncthreads();
    if (i < NN) {
        float fi0 = f0[i], fi1 = f1[i];
        int exi = ex[i];
        float deg = 0.f;
        for (int j = 0; j < NN; ++j) {
            float dx = fi0 - f0[j], dy = fi1 - f1[j];
            float a = (i == j) ? 1.0f :
                      ((dx * dx + dy * dy <= 100.0f && exi && ex[j]) ? 1.0f : 0.0f);
            deg += a;
        }
        sdinv[i] = rsqrtf(deg);
    }
    __syncthreads();
    if (i < NN) {
        float fi0 = f0[i], fi1 = f1[i];
        int exi = ex[i];
        float a0 = 0.f, a1 = 0.f;
        for (int j = 0; j < NN; ++j) {
            float dx = fi0 - f0[j], dy = fi1 - f1[j];
            float a = (i == j) ? 1.0f :
                      ((dx * dx + dy * dy <= 100.0f && exi && ex[j]) ? 1.0f : 0.0f);
            float an = a * sdinv[j];
            a0 += an * sxw0[j];
            a1 += an * sxw1[j];
        }
        float di = sdinv[i];
        gT[(i * 2 + 0) * 64 + b] = a0 * di + bg[0];
        gT[(i * 2 + 1) * 64 + b] = a1 * di + bg[1];
    }
}

// ==================== bf16 pack: W (NO,K) -> Bp[(k>>3)][n][k&7] ====================
__global__ void pack_b_kernel(const float* __restrict__ W, unsigned short* __restrict__ Bp,
                              int NO, int K) {
    int t = blockIdx.x * blockDim.x + threadIdx.x;
    int kgs = K >> 3;
    if (t >= NO * kgs) return;
    int kg = t % kgs;
    int n  = t / kgs;
    const float* src = W + (size_t)n * K + (size_t)kg * 8;
    unsigned short* dst = Bp + ((size_t)kg * NO + n) * 8;
    #pragma unroll
    for (int j = 0; j < 8; ++j) dst[j] = f2bf(src[j]);
}

// ==================== batched MFMA MLP layer (encoder frames, M=640) ====================
// inb: (640, K) bf16 row-major. Bp packed. outb: (640, NO) bf16 or null.
// frames: base of output frame 1 (fp32 std layout) or null.
__global__ __launch_bounds__(256) void gemm_mfma(
    const unsigned short* __restrict__ inb,
    const unsigned short* __restrict__ Bp,
    const float* __restrict__ bias,
    unsigned short* __restrict__ outb,
    float* __restrict__ frames,
    int K, int NO, int relu)
{
    __shared__ unsigned short lds_a[64][72];   // 64 m x 64 k, pad to 72
    int tid = threadIdx.x;
    int lane = tid & 63;
    int w = tid >> 6;
    int m0 = blockIdx.y * 64;
    int nb = blockIdx.x * 64;
    int l15 = lane & 15;
    int lq  = lane >> 4;   // 0..3
    int n = nb + w * 16 + l15;
    f32x4 acc[4] = {};

    for (int k0 = 0; k0 < K; k0 += 64) {
        if (k0) __syncthreads();
        #pragma unroll
        for (int p = 0; p < 2; ++p) {
            int idx = tid + p * 256;          // 0..511
            int m = idx >> 3, kq = idx & 7;
            *(s16x8*)&lds_a[m][kq * 8] =
                *(const s16x8*)&inb[(size_t)(m0 + m) * K + k0 + kq * 8];
        }
        __syncthreads();
        #pragma unroll
        for (int sub = 0; sub < 2; ++sub) {
            int kk = sub * 32 + lq * 8;
            s16x8 bfr = *(const s16x8*)&Bp[((size_t)((k0 + kk) >> 3) * NO + n) * 8];
            #pragma unroll
            for (int s = 0; s < 4; ++s) {
                s16x8 afr = *(const s16x8*)&lds_a[s * 16 + l15][kk];
                acc[s] = __builtin_amdgcn_mfma_f32_16x16x32_bf16(afr, bfr, acc[s], 0, 0, 0);
            }
        }
    }
    float bn = bias[n];
    #pragma unroll
    for (int s = 0; s < 4; ++s) {
        #pragma unroll
        for (int r = 0; r < 4; ++r) {
            int m = m0 + s * 16 + lq * 4 + r;
            float v = acc[s][r] + bn;
            if (relu) v = fmaxf(v, 0.f);
            if (outb) outb[(size_t)m * NO + n] = f2bf(v);
            if (frames && m < 576) {
                int f = m >> 6, b = m & 63;
                frames[(size_t)f * FRAME_ELEMS + b * 128 + n] = v;
            }
        }
    }
}

// ==================== host ====================

extern "C" void kernel_launch(void* const* d_in, const int* in_sizes, int n_in,
                              void* d_out, int out_size, void* d_ws, size_t ws_size,
                              hipStream_t stream) {
    const float* feat   = (const float*)d_in[0];
    const int*   ei_in  = (const int*)d_in[1];
    const float* stats  = (const float*)d_in[4];
    const float* w_gcn  = (const float*)d_in[5];
    const float* b_gcn  = (const float*)d_in[6];
    const float* w_ih   = (const float*)d_in[7];
    const float* w_hh   = (const float*)d_in[8];
    const float* b_ih   = (const float*)d_in[9];
    const float* b_hh   = (const float*)d_in[10];
    const float* wm[6], *bm[6];
    for (int i = 0; i < 6; ++i) { wm[i] = (const float*)d_in[11 + 2*i]; bm[i] = (const float*)d_in[12 + 2*i]; }
    const int mlp_K[6]  = {1024, 2048, 4096, 2048, 1024, 512};
    const int mlp_NO[6] = {2048, 4096, 2048, 1024, 512, 128};

    float* out = (float*)d_out;
    float* ws  = (float*)d_ws;

    // ---------- workspace layout (floats) ----------
    size_t off = 0;
    float* wt_ih = ws + off; off += (size_t)128 * 4096;
    float* wt_hh = ws + off; off += (size_t)1024 * 4096;
    float* wt[6];
    const size_t wt_sz[6] = {(size_t)1024*2048, (size_t)2048*4096, (size_t)4096*2048,
                             (size_t)2048*1024, (size_t)1024*512, (size_t)512*128};
    for (int i = 0; i < 6; ++i) { wt[i] = ws + off; off += wt_sz[i]; }
    float* P      = ws + off; off += (size_t)9 * 4096 * 64;   // 2.36M floats (LSTM is max user)
    float* gT_all = ws + off; off += (size_t)10 * 128 * 64;
    float* gT_dec = ws + off; off += 8192;
    float* hT     = ws + off; off += 65536;
    float* cT     = ws + off; off += 65536;
    float* aT1    = ws + off; off += 131072;
    float* aT2    = ws + off; off += 262144;
    float* aT3    = ws + off; off += 131072;
    float* aT4    = ws + off; off += 65536;
    float* aT5    = ws + off; off += 32768;
    float* deg    = ws + off; off += (size_t)10 * 4096;
    float* xw     = ws + off; off += (size_t)10 * 8192;
    float* inb1f  = ws + off; off += 327680;                  // 640*1024 bf16
    size_t need_bytes = off * sizeof(float);
    if (ws_size < need_bytes) return;

    // bf16 views: inb1 separate; inb2..6 alias the P..xw scratch region (dead in final phase)
    unsigned short* inb1 = (unsigned short*)inb1f;
    unsigned short* inb2 = (unsigned short*)P;
    unsigned short* inb3 = inb2 + (size_t)640 * 2048;
    unsigned short* inb4 = inb3 + (size_t)640 * 4096;
    unsigned short* inb5 = inb4 + (size_t)640 * 2048;
    unsigned short* inb6 = inb5 + (size_t)640 * 1024;
    // Bp packed weights alias the fp32 wt region (dead after step 14)
    unsigned short* Bp[6];
    {
        unsigned short* base = (unsigned short*)wt[0];
        size_t boff = 0;
        for (int l = 0; l < 6; ++l) { Bp[l] = base + boff; boff += (size_t)mlp_NO[l] * mlp_K[l]; }
    }

    hipMemsetAsync(hT, 0, 2 * 65536 * sizeof(float), stream);
    hipMemsetAsync(inb1, 0, (size_t)640 * 1024 * sizeof(unsigned short), stream);
    hipMemcpyAsync(out, feat, FRAME_ELEMS * sizeof(float), hipMemcpyDeviceToDevice, stream);

    // ---------- upfront: weight transposes (fp32 path) ----------
    transpose_kernel<<<dim3(128 / 32, 4096 / 32), 256, 0, stream>>>(w_ih, wt_ih, 4096, 128);
    transpose_kernel<<<dim3(1024 / 32, 4096 / 32), 256, 0, stream>>>(w_hh, wt_hh, 4096, 1024);
    for (int l = 0; l < 6; ++l)
        transpose_kernel<<<dim3(mlp_K[l] / 32, mlp_NO[l] / 32), 256, 0, stream>>>(wm[l], wt[l], mlp_NO[l], mlp_K[l]);

    // ---------- upfront: batched GCN for all 10 input frames ----------
    bgcn_init_xw<<<10 * NTOT / 256, 256, 0, stream>>>(feat, w_gcn, deg, xw);
    bgcn_count<<<10 * NEDGE / 256, 256, 0, stream>>>(ei_in, deg);
    bgcn_node<<<10 * NTOT / 256, 256, 0, stream>>>(b_gcn, deg, xw, gT_all);
    bgcn_scatter<<<10 * NEDGE / 256, 256, 0, stream>>>(ei_in, deg, xw, gT_all);

    // ---------- 15 serial steps ----------
    for (int s = 0; s < 15; ++s) {
        const float* gT_s = (s <= 9) ? (gT_all + (size_t)s * 8192) : gT_dec;

        // LSTM: ks 0..7 = hh chunks (K=1024, KC=128), ks 8 = ih (K=128)
        gemm_bx3<128><<<dim3(64, 9), 256, 0, stream>>>(hT, gT_s, wt_hh, wt_ih, P, 4096, 8);
        lstm_update2<<<HDIM * BSZ / 256, 256, 0, stream>>>(
            P, b_ih, b_hh, hT, cT, (s <= 8) ? inb1 : nullptr, s * 64);

        if (s >= 9) {
            // decoder: full fp32 MLP (feedback-safe)
            float* frame = out + (size_t)(s + 1) * FRAME_ELEMS;
            gemm_bx3<64><<<dim3(32, 16), 256, 0, stream>>>(hT, nullptr, wt[0], nullptr, P, 2048, 16);
            reduce_relu_kernel<<<2048 * 64 / 256, 256, 0, stream>>>(P, bm[0], aT1, 2048, 16, 1);
            gemm_bx3<256><<<dim3(64, 8), 256, 0, stream>>>(aT1, nullptr, wt[1], nullptr, P, 4096, 8);
            reduce_relu_kernel<<<4096 * 64 / 256, 256, 0, stream>>>(P, bm[1], aT2, 4096, 8, 1);
            gemm_bx3<256><<<dim3(32, 16), 256, 0, stream>>>(aT2, nullptr, wt[2], nullptr, P, 2048, 16);
            reduce_relu_kernel<<<2048 * 64 / 256, 256, 0, stream>>>(P, bm[2], aT3, 2048, 16, 1);
            gemm_bx3<128><<<dim3(16, 16), 256, 0, stream>>>(aT3, nullptr, wt[3], nullptr, P, 1024, 16);
            reduce_relu_kernel<<<1024 * 64 / 256, 256, 0, stream>>>(P, bm[3], aT4, 1024, 16, 1);
            gemm_bx3<64><<<dim3(8, 16), 256, 0, stream>>>(aT4, nullptr, wt[4], nullptr, P, 512, 16);
            reduce_relu_kernel<<<512 * 64 / 256, 256, 0, stream>>>(P, bm[4], aT5, 512, 16, 1);
            gemm_bx3<64><<<dim3(2, 8), 256, 0, stream>>>(aT5, nullptr, wt[5], nullptr, P, 128, 8);
            if (s < 14) {
                finalize_dec<<<BSZ, 128, 0, stream>>>(P, bm[5], stats, w_gcn, b_gcn, frame, gT_dec, 8);
            } else {
                finalize_enc<<<BSZ, 128, 0, stream>>>(P, bm[5], frame, 8);
            }
        }
    }

    // ---------- batched encoder MLP (frames 1..9), bf16 MFMA ----------
    // pack weights (overwrites fp32 wt region — dead now)
    for (int l = 0; l < 6; ++l) {
        int total = mlp_NO[l] * (mlp_K[l] >> 3);
        pack_b_kernel<<<(total + 255) / 256, 256, 0, stream>>>(wm[l], Bp[l], mlp_NO[l], mlp_K[l]);
    }
    unsigned short* chain_in[6]  = {inb1, inb2, inb3, inb4, inb5, inb6};
    unsigned short* chain_out[6] = {inb2, inb3, inb4, inb5, inb6, nullptr};
    for (int l = 0; l < 6; ++l) {
        gemm_mfma<<<dim3(mlp_NO[l] / 64, 10), 256, 0, stream>>>(
            chain_in[l], Bp[l], bm[l], chain_out[l],
            (l == 5) ? (out + FRAME_ELEMS) : nullptr,
            mlp_K[l], mlp_NO[l], l < 5 ? 1 : 0);
    }
}